// Round 10
// baseline (428.075 us; speedup 1.0000x reference)
//
#include <hip/hip_runtime.h>

// Problem constants (from reference)
#define B_  16
#define T_  2048
#define IN_ 512
#define H_  512
#define M_  (B_ * T_)

// R19: fusion round 4. R18 fixed regalloc (VGPR 128, no spill) but fused
// dispatch = 357us with VALU-WORK CONSERVED (0.39x357 == 0.67x209) ->
// pure idle added = straggler CUs: the 32 consumer blocks land as a 3rd
// block on ~32 CUs, scan waves steal ~1/3 of issue there, those producers
// run 1.5x slow, dispatch waits on them.
// Fix: s_setprio(1) for the ENTIRE producer path. Consumer waves (prio 0)
// then only issue into GEMM stall bubbles (~30% barrier/waitcnt drain)
// instead of round-robin stealing. Role-diverse setprio regime (m191-class).
// Everything else byte-identical to R18 (protocol validated: absmax 0.0).
#define BM 128
#define BN 128
#define BK 16
#define LDT (BM + 4)

#define NGEMM 512   // gemm blocks, 2 tiles each = 1024 tiles
#define NSCAN 32    // scan blocks x 256 threads = 8192 chains

// Tile-ready flags, one producer each; two consumer waves -> two copies, each
// consumed-and-RESET by exactly one wave => self-cleaning across graph
// replays (device globals zero-init at load; kernel exits all-zero).
// Protocol hardware-validated in R16/R18 (passed, absmax 0.0).
__device__ unsigned g_flagA[1024];
__device__ unsigned g_flagB[1024];

static __device__ __forceinline__ float4 ld4(const float* p) {
    return *reinterpret_cast<const float4*>(p);
}

// ---------------------------------------------------------------------------
// One GEMM tile: h[m0:+128][n0:+128]. Body verbatim from the validated
// kernel (absmax 0.0 across R2-R18). k accumulated strictly in order 0..511
// with fmaf. DO NOT reorder the k loop.
// ---------------------------------------------------------------------------
__device__ __forceinline__
void gemm_tile(const float* __restrict__ X, const float* __restrict__ W,
               const float* __restrict__ bias, float* __restrict__ Hout,
               int m0, int n0, int tid,
               float (*As)[LDT], float (*Bs)[LDT]) {
    const int tx = tid & 15;           // col group
    const int ty = tid >> 4;           // row group

    const int row = tid >> 2;          // 0..63
    const int kph = (tid & 3) * 4;     // 0,4,8,12

    const float* pa0 = X + (size_t)(m0 + row) * IN_ + kph;
    const float* pa1 = pa0 + (size_t)64 * IN_;
    const float* pb0 = W + (size_t)(n0 + row) * IN_ + kph;
    const float* pb1 = pb0 + (size_t)64 * IN_;

    float4 ra0 = ld4(pa0), ra1 = ld4(pa1), rb0 = ld4(pb0), rb1 = ld4(pb1);

    float acc[8][8];
#pragma unroll
    for (int i = 0; i < 8; ++i)
#pragma unroll
        for (int j = 0; j < 8; ++j) acc[i][j] = 0.0f;

    for (int k0 = 0; k0 < IN_; k0 += BK) {
        As[kph + 0][row]      = ra0.x;  As[kph + 1][row]      = ra0.y;
        As[kph + 2][row]      = ra0.z;  As[kph + 3][row]      = ra0.w;
        As[kph + 0][row + 64] = ra1.x;  As[kph + 1][row + 64] = ra1.y;
        As[kph + 2][row + 64] = ra1.z;  As[kph + 3][row + 64] = ra1.w;
        Bs[kph + 0][row]      = rb0.x;  Bs[kph + 1][row]      = rb0.y;
        Bs[kph + 2][row]      = rb0.z;  Bs[kph + 3][row]      = rb0.w;
        Bs[kph + 0][row + 64] = rb1.x;  Bs[kph + 1][row + 64] = rb1.y;
        Bs[kph + 2][row + 64] = rb1.z;  Bs[kph + 3][row + 64] = rb1.w;
        __syncthreads();

        // prefetch next k-tile into registers; drains during the 16-k compute
        if (k0 + BK < IN_) {
            ra0 = ld4(pa0 + k0 + BK);  ra1 = ld4(pa1 + k0 + BK);
            rb0 = ld4(pb0 + k0 + BK);  rb1 = ld4(pb1 + k0 + BK);
        }

#pragma unroll
        for (int k = 0; k < BK; ++k) {
            float4 av0 = ld4(&As[k][ty * 4]);
            float4 av1 = ld4(&As[k][ty * 4 + 64]);
            float4 bv0 = ld4(&Bs[k][tx * 4]);
            float4 bv1 = ld4(&Bs[k][tx * 4 + 64]);
            const float am[8] = {av0.x, av0.y, av0.z, av0.w,
                                 av1.x, av1.y, av1.z, av1.w};
            const float bn8[8] = {bv0.x, bv0.y, bv0.z, bv0.w,
                                  bv1.x, bv1.y, bv1.z, bv1.w};
#pragma unroll
            for (int i = 0; i < 8; ++i)
#pragma unroll
                for (int j = 0; j < 8; ++j)
                    acc[i][j] = fmaf(am[i], bn8[j], acc[i][j]);
        }
        __syncthreads();
    }

    // epilogue: + bias (bias is zeros -> exact), coalesced float4 stores
    float4 bb0 = ld4(&bias[n0 + tx * 4]);
    float4 bb1 = ld4(&bias[n0 + tx * 4 + 64]);
#pragma unroll
    for (int i = 0; i < 8; ++i) {
        const int r2 = m0 + ((i < 4) ? (ty * 4 + i) : (64 + ty * 4 + (i - 4)));
        float4 o0, o1;
        o0.x = acc[i][0] + bb0.x;  o0.y = acc[i][1] + bb0.y;
        o0.z = acc[i][2] + bb0.z;  o0.w = acc[i][3] + bb0.w;
        o1.x = acc[i][4] + bb1.x;  o1.y = acc[i][5] + bb1.y;
        o1.z = acc[i][6] + bb1.z;  o1.w = acc[i][7] + bb1.w;
        *reinterpret_cast<float4*>(&Hout[(size_t)r2 * H_ + n0 + tx * 4])      = o0;
        *reinterpret_cast<float4*>(&Hout[(size_t)r2 * H_ + n0 + tx * 4 + 64]) = o1;
    }
}

// ---------------------------------------------------------------------------
// Scan step batch (16 steps). Arithmetic statements byte-identical to the
// validated R10-R18 step (absmax 0.0). DO NOT touch.
// ---------------------------------------------------------------------------
__device__ __forceinline__
void scan_compute16(const float* __restrict__ buf, float* __restrict__ sarr,
                    float& v, float& theta) {
    const float DECAY_F = 0.9048374180359595f;  // exp(-1/10)
    const float ALPHA_F = 0.01f;
#pragma unroll
    for (int j = 0; j < 16; ++j) {
        float cur = buf[j];
        v = v * DECAY_F + cur;
        float cl = 32.0f * theta;                  // L * theta * 2
        v = __builtin_amdgcn_fmed3f(v, -cl, cl);   // == fminf(fmaxf(v,-cl),cl)

        // ---- v/theta: raw rcp seed + Markstein correction (validated) ----
        float r0 = __builtin_amdgcn_rcpf(theta);   // ~1 ulp seed
        float q0 = v * r0;
        float er = fmaf(-theta, q0, v);            // exact residual
        float q  = fmaf(er, r0, q0);               // RN quotient to O(ulp^2)
        // ------------------------------------------------------------------

        float s = floorf(q);
        s = __builtin_amdgcn_fmed3f(s, 0.0f, 16.0f); // == fminf(fmaxf(s,0),16)
        v = v - s * theta;
        theta = theta + ALPHA_F * s - ALPHA_F * (theta - 1.0f);
        sarr[j] = s;                               // register array
    }
}

// ---------------------------------------------------------------------------
// Fused kernel. Blocks 0..511: persistent GEMM producers at WAVE PRIORITY 1
// (2 tiles, t-major phases, publish flag per tile). Blocks 512..543: scan
// consumers at priority 0 — issue only into producer stall bubbles on shared
// CUs. amdgpu_waves_per_eu(2,3) keeps regalloc >= ~170 target (R18: VGPR
// 128, no spill). 544 blocks co-resident; producers never wait on consumers.
// ---------------------------------------------------------------------------
__global__
__attribute__((amdgpu_flat_work_group_size(256, 256), amdgpu_waves_per_eu(2, 3)))
void fused_gemm_scan(const float* __restrict__ X, const float* __restrict__ W,
                     const float* __restrict__ bias, float* __restrict__ Hbuf,
                     float* __restrict__ spikes, float* __restrict__ vout,
                     float* __restrict__ thout) {
    __shared__ float As[BK][LDT];
    __shared__ float Bs[BK][LDT];

    if (blockIdx.x < NGEMM) {
        // ------- producer: 2 GEMM tiles, t-major, elevated priority -------
        __builtin_amdgcn_s_setprio(1);
        const int tid = threadIdx.x;
        const int g   = blockIdx.x;        // 0..511
        const int tt7 = g >> 6;            // 0..7  (t-octile -> early t first)
        const int bb  = (g >> 2) & 15;     // batch
        const int nt  = g & 3;             // n-tile
#pragma unroll 1
        for (int ph = 0; ph < 2; ++ph) {
            const int tt = tt7 + ph * 8;   // 0..15
            const int mt = bb * 16 + tt;   // m-tile = (b, t-chunk)
            gemm_tile(X, W, bias, Hbuf, mt * BM, nt * BN, tid, As, Bs);
            __syncthreads();               // wave convergence before publish
            if (tid == 0) {
                const int tau = mt * 4 + nt;
                __hip_atomic_store(&g_flagA[tau], 1u, __ATOMIC_RELEASE,
                                   __HIP_MEMORY_SCOPE_AGENT);
                __hip_atomic_store(&g_flagB[tau], 1u, __ATOMIC_RELEASE,
                                   __HIP_MEMORY_SCOPE_AGENT);
            }
        }
        __builtin_amdgcn_s_setprio(0);
    } else {
        // ---------------- consumer: GIF scan, flag-gated chunks ----------
        const int s   = blockIdx.x - NGEMM;
        const int gid = s * 256 + (int)threadIdx.x;   // 0..8191
        const int b   = gid >> 9;
        const int h   = gid & 511;

        const float* ip = Hbuf   + (size_t)b * T_ * H_ + h;
        float*       sp = spikes + (size_t)b * T_ * H_ + h;

        // wave-uniform flag selection: h>>6 parity picks the copy,
        // h>>7 picks the n-tile. (64-lane wave spans one 64-aligned h range.)
        unsigned* flagbase = ((h >> 6) & 1) ? g_flagB : g_flagA;
        const int ntq = h >> 7;

        float bufA[16], bufB[16], sA[16], sB[16];
        float v = 0.0f, theta = 1.0f;

        for (int c = 0; c < 16; ++c) {            // 16 chunks of 128 t
            const int t0 = c * 128;
            unsigned* fp = flagbase + ((size_t)(b * 16 + c) * 4 + ntq);
            while (__hip_atomic_load(fp, __ATOMIC_ACQUIRE,
                                     __HIP_MEMORY_SCOPE_AGENT) == 0u)
                __builtin_amdgcn_s_sleep(8);
            // consume-and-reset (self-cleaning for the next graph replay)
            __hip_atomic_store(fp, 0u, __ATOMIC_RELAXED,
                               __HIP_MEMORY_SCOPE_AGENT);

            // 8 batches of 16 steps, double-buffered (R11 pattern, validated)
#pragma unroll
            for (int j = 0; j < 16; ++j) bufA[j] = ip[(size_t)(t0 + j) * H_];
            for (int bt = 0; bt < 8; bt += 2) {
#pragma unroll
                for (int j = 0; j < 16; ++j)
                    bufB[j] = ip[(size_t)(t0 + (bt + 1) * 16 + j) * H_];
                asm volatile("" ::: "memory");
                scan_compute16(bufA, sA, v, theta);
#pragma unroll
                for (int j = 0; j < 16; ++j)
                    sp[(size_t)(t0 + bt * 16 + j) * H_] = sA[j];

                if (bt + 2 < 8) {
#pragma unroll
                    for (int j = 0; j < 16; ++j)
                        bufA[j] = ip[(size_t)(t0 + (bt + 2) * 16 + j) * H_];
                }
                asm volatile("" ::: "memory");
                scan_compute16(bufB, sB, v, theta);
#pragma unroll
                for (int j = 0; j < 16; ++j)
                    sp[(size_t)(t0 + (bt + 1) * 16 + j) * H_] = sB[j];
            }
        }
        vout[gid]  = v;
        thout[gid] = theta;
    }
}

// ---------------------------------------------------------------------------
extern "C" void kernel_launch(void* const* d_in, const int* in_sizes, int n_in,
                              void* d_out, int out_size, void* d_ws, size_t ws_size,
                              hipStream_t stream) {
    const float* x    = (const float*)d_in[0];   // [16, 2048, 512]
    const float* W    = (const float*)d_in[1];   // [512, 512]
    const float* bias = (const float*)d_in[2];   // [512]

    float* out    = (float*)d_out;
    float* spikes = out;
    float* v_f    = out + (size_t)M_ * H_;
    float* th_f   = v_f + (size_t)B_ * H_;

    float* hbuf   = (float*)d_ws;                // 64 MiB scratch for h

    fused_gemm_scan<<<NGEMM + NSCAN, 256, 0, stream>>>(
        x, W, bias, hbuf, spikes, v_f, th_f);
}

// Round 11
// 370.617 us; speedup vs baseline: 1.1550x; 1.1550x over previous
//
#include <hip/hip_runtime.h>

// Problem constants (from reference)
#define B_  16
#define T_  2048
#define IN_ 512
#define H_  512
#define M_  (B_ * T_)

// FINAL CONFIGURATION (R20) — byte-identical codegen to the round-6 bench
// (368.59us, session best). Session ledger:
//   GEMM: R5 structure + R15 XCD swizzle = 207-209us local optimum.
//     R6 launch-bounds(256,4): acc spill -> 3048. R7 reg ping-pong: 298.
//     R9 1-barrier ping-pong: 230. R13 half-grids: +14us. R17 BK=32: 216
//     (and LDS conflicts 0 with NO speedup -> conflicts were never the cost).
//     R15 swizzle: FETCH 122.5->42.8MB, time null -> not fetch-bound.
//     Equilibrium: FMA floor 109us + staging VALU + barrier drain; VALU 67%.
//   SCAN: R11 form, <112us dispatch (R13 bound), latency-structural.
//     R10 shorter chain: null. R11 batched stores: ~null. R12 LDS transpose
//     4x fewer vmem: null. R14 2-chain ILP: serialized -> 428.
//   FUSION: dead. R8 529, R16 812 (regalloc spill, WRITE ~1GB), R18 357
//     (VALU-work conserved -> pure idle added), R19 +setprio 355 (null ->
//     contention is memory-pipe, not issue arbitration). Fused dispatch
//     never beat the serial dispatch-sum (~314us).
#define BM 128
#define BN 128
#define BK 16
#define LDT (BM + 4)

static __device__ __forceinline__ float4 ld4(const float* p) {
    return *reinterpret_cast<const float4*>(p);
}

// ---------------------------------------------------------------------------
// Kernel 1: h[m][n] = sum_k x[m][k]*W[n][k] + b[n], fp32 VALU.
// k accumulated strictly in order 0..511 with fmaf -> bit-matches np ref
// (absmax 0.0 across R2-R19). DO NOT reorder the k loop.
// ---------------------------------------------------------------------------
__global__ __launch_bounds__(256)
void gemm_xwT(const float* __restrict__ X, const float* __restrict__ W,
              const float* __restrict__ bias, float* __restrict__ Hout) {
    __shared__ float As[BK][LDT];
    __shared__ float Bs[BK][LDT];

    const int tid = threadIdx.x;

    // R15 XCD-aware swizzle (validated: FETCH 122.5->42.8MB, bijective).
    const int L  = blockIdx.y * gridDim.x + blockIdx.x;   // 0..1023
    const int r  = L & 7;
    const int q  = L >> 3;
    const int mt = r + 8 * (q >> 2);   // 0..255
    const int nt = q & 3;              // 0..3
    const int m0 = mt * BM;
    const int n0 = nt * BN;

    const int tx = tid & 15;           // col group
    const int ty = tid >> 4;           // row group

    const int row = tid >> 2;          // 0..63
    const int kph = (tid & 3) * 4;     // 0,4,8,12

    const float* pa0 = X + (size_t)(m0 + row) * IN_ + kph;
    const float* pa1 = pa0 + (size_t)64 * IN_;
    const float* pb0 = W + (size_t)(n0 + row) * IN_ + kph;
    const float* pb1 = pb0 + (size_t)64 * IN_;

    float4 ra0 = ld4(pa0), ra1 = ld4(pa1), rb0 = ld4(pb0), rb1 = ld4(pb1);

    float acc[8][8];
#pragma unroll
    for (int i = 0; i < 8; ++i)
#pragma unroll
        for (int j = 0; j < 8; ++j) acc[i][j] = 0.0f;

    for (int k0 = 0; k0 < IN_; k0 += BK) {
        As[kph + 0][row]      = ra0.x;  As[kph + 1][row]      = ra0.y;
        As[kph + 2][row]      = ra0.z;  As[kph + 3][row]      = ra0.w;
        As[kph + 0][row + 64] = ra1.x;  As[kph + 1][row + 64] = ra1.y;
        As[kph + 2][row + 64] = ra1.z;  As[kph + 3][row + 64] = ra1.w;
        Bs[kph + 0][row]      = rb0.x;  Bs[kph + 1][row]      = rb0.y;
        Bs[kph + 2][row]      = rb0.z;  Bs[kph + 3][row]      = rb0.w;
        Bs[kph + 0][row + 64] = rb1.x;  Bs[kph + 1][row + 64] = rb1.y;
        Bs[kph + 2][row + 64] = rb1.z;  Bs[kph + 3][row + 64] = rb1.w;
        __syncthreads();

        // prefetch next k-tile into registers; drains during the 16-k compute
        if (k0 + BK < IN_) {
            ra0 = ld4(pa0 + k0 + BK);  ra1 = ld4(pa1 + k0 + BK);
            rb0 = ld4(pb0 + k0 + BK);  rb1 = ld4(pb1 + k0 + BK);
        }

#pragma unroll
        for (int k = 0; k < BK; ++k) {
            float4 av0 = ld4(&As[k][ty * 4]);
            float4 av1 = ld4(&As[k][ty * 4 + 64]);
            float4 bv0 = ld4(&Bs[k][tx * 4]);
            float4 bv1 = ld4(&Bs[k][tx * 4 + 64]);
            const float am[8] = {av0.x, av0.y, av0.z, av0.w,
                                 av1.x, av1.y, av1.z, av1.w};
            const float bn8[8] = {bv0.x, bv0.y, bv0.z, bv0.w,
                                  bv1.x, bv1.y, bv1.z, bv1.w};
#pragma unroll
            for (int i = 0; i < 8; ++i)
#pragma unroll
                for (int j = 0; j < 8; ++j)
                    acc[i][j] = fmaf(am[i], bn8[j], acc[i][j]);
        }
        __syncthreads();
    }

    // epilogue: + bias (bias is zeros -> exact), coalesced float4 stores
    float4 bb0 = ld4(&bias[n0 + tx * 4]);
    float4 bb1 = ld4(&bias[n0 + tx * 4 + 64]);
#pragma unroll
    for (int i = 0; i < 8; ++i) {
        const int r2 = m0 + ((i < 4) ? (ty * 4 + i) : (64 + ty * 4 + (i - 4)));
        float4 o0, o1;
        o0.x = acc[i][0] + bb0.x;  o0.y = acc[i][1] + bb0.y;
        o0.z = acc[i][2] + bb0.z;  o0.w = acc[i][3] + bb0.w;
        o1.x = acc[i][4] + bb1.x;  o1.y = acc[i][5] + bb1.y;
        o1.z = acc[i][6] + bb1.z;  o1.w = acc[i][7] + bb1.w;
        *reinterpret_cast<float4*>(&Hout[(size_t)r2 * H_ + n0 + tx * 4])      = o0;
        *reinterpret_cast<float4*>(&Hout[(size_t)r2 * H_ + n0 + tx * 4 + 64]) = o1;
    }
}

// ---------------------------------------------------------------------------
// Kernel 2: GIF neuron scan. One thread per (b,h) chain; T=2048 steps.
// R11 form — session-best validated. 128 waves, register double-buffers,
// pure-ALU compute phase, bulk batch stores.
// R10-R14 established: not ALU-chain-bound, not store-hazard-bound, not
// vmem-count-bound, not per-thread-ILP-improvable. LEAVE AS IS.
// Arithmetic statements byte-identical to R10-R19 (absmax 0.0). DO NOT touch.
// ---------------------------------------------------------------------------
#define SPF 32

__device__ __forceinline__
void scan_compute(const float* __restrict__ buf, float* __restrict__ sarr,
                  float& v, float& theta) {
    const float DECAY_F = 0.9048374180359595f;  // exp(-1/10)
    const float ALPHA_F = 0.01f;
#pragma unroll
    for (int j = 0; j < SPF; ++j) {
        float cur = buf[j];
        v = v * DECAY_F + cur;
        float cl = 32.0f * theta;                  // L * theta * 2
        v = __builtin_amdgcn_fmed3f(v, -cl, cl);   // == fminf(fmaxf(v,-cl),cl)

        // ---- v/theta: raw rcp seed + Markstein correction (validated) ----
        float r0 = __builtin_amdgcn_rcpf(theta);   // ~1 ulp seed
        float q0 = v * r0;
        float er = fmaf(-theta, q0, v);            // exact residual
        float q  = fmaf(er, r0, q0);               // RN quotient to O(ulp^2)
        // ------------------------------------------------------------------

        float s = floorf(q);
        s = __builtin_amdgcn_fmed3f(s, 0.0f, 16.0f); // == fminf(fmaxf(s,0),16)
        v = v - s * theta;
        theta = theta + ALPHA_F * s - ALPHA_F * (theta - 1.0f);
        sarr[j] = s;                               // register array, no store
    }
}

__device__ __forceinline__
void store_batch(float* __restrict__ sp, int tb, const float* __restrict__ sarr) {
#pragma unroll
    for (int j = 0; j < SPF; ++j)
        sp[(size_t)(tb + j) * H_] = sarr[j];
}

__global__ __launch_bounds__(64, 1)
void gif_scan(const float* __restrict__ Hbuf, float* __restrict__ spikes,
              float* __restrict__ vout, float* __restrict__ thout) {
    const int gid = blockIdx.x * 64 + threadIdx.x;    // 0..8191
    const int b = gid >> 9;
    const int h = gid & 511;

    const float* ip = Hbuf   + (size_t)b * T_ * H_ + h;
    float*       sp = spikes + (size_t)b * T_ * H_ + h;

    float bufA[SPF], bufB[SPF], sA[SPF], sB[SPF];
#pragma unroll
    for (int j = 0; j < SPF; ++j) bufA[j] = ip[(size_t)j * H_];

    float v = 0.0f, theta = 1.0f;
    for (int t0 = 0; t0 < T_; t0 += 2 * SPF) {        // 32 iters, no tail
        // prefetch next half-batch
#pragma unroll
        for (int j = 0; j < SPF; ++j) bufB[j] = ip[(size_t)(t0 + SPF + j) * H_];
        asm volatile("" ::: "memory");

        scan_compute(bufA, sA, v, theta);             // pure ALU
        store_batch(sp, t0, sA);                      // 32 bulk stores

        if (t0 + 2 * SPF < T_) {
#pragma unroll
            for (int j = 0; j < SPF; ++j)
                bufA[j] = ip[(size_t)(t0 + 2 * SPF + j) * H_];
        }
        asm volatile("" ::: "memory");

        scan_compute(bufB, sB, v, theta);             // pure ALU
        store_batch(sp, t0 + SPF, sB);                // 32 bulk stores
    }
    vout[gid]  = v;
    thout[gid] = theta;
}

// ---------------------------------------------------------------------------
extern "C" void kernel_launch(void* const* d_in, const int* in_sizes, int n_in,
                              void* d_out, int out_size, void* d_ws, size_t ws_size,
                              hipStream_t stream) {
    const float* x    = (const float*)d_in[0];   // [16, 2048, 512]
    const float* W    = (const float*)d_in[1];   // [512, 512]
    const float* bias = (const float*)d_in[2];   // [512]

    float* out    = (float*)d_out;
    float* spikes = out;
    float* v_f    = out + (size_t)M_ * H_;
    float* th_f   = v_f + (size_t)B_ * H_;

    float* hbuf   = (float*)d_ws;                // 64 MiB scratch for h

    dim3 grid(M_ / BM, H_ / BN);                 // 256 x 4, single launch
    gemm_xwT<<<grid, 256, 0, stream>>>(x, W, bias, hbuf);
    gif_scan<<<(B_ * H_) / 64, 64, 0, stream>>>(hbuf, spikes, v_f, th_f);
}